// Round 13
// baseline (1205.574 us; speedup 1.0000x reference)
//
#include <hip/hip_runtime.h>
#include <hip/hip_bf16.h>

#define D_MODEL 4096
#define D_FF    11008
#define NTOK    4096   // 2*2048 tokens

typedef __attribute__((ext_vector_type(8))) short short8;
typedef __attribute__((ext_vector_type(4))) float f32x4;

// ---------------- fp32 -> bf16 convert (8 elems/thread) — X only --------
__global__ void k_cvt(const float* __restrict__ in, __hip_bfloat16* __restrict__ out, int n8) {
    int i = blockIdx.x * blockDim.x + threadIdx.x;
    if (i >= n8) return;
    const float4* p = (const float4*)in;
    float4 v0 = p[(size_t)i * 2];
    float4 v1 = p[(size_t)i * 2 + 1];
    float vals[8] = {v0.x, v0.y, v0.z, v0.w, v1.x, v1.y, v1.z, v1.w};
    short8 o;
#pragma unroll
    for (int j = 0; j < 8; ++j) {
        __hip_bfloat16 b = __float2bfloat16(vals[j]);
        o[j] = *reinterpret_cast<short*>(&b);
    }
    *reinterpret_cast<short8*>(out + (size_t)i * 8) = o;
}

// ---- stage one 128x64 bf16 half-tile via global_load_lds ----
// LDS dest linear; swizzle via permuted GLOBAL source chunk (rule #21):
// physical chunk p of row r holds logical chunk p ^ (r&7).
static __device__ __forceinline__ void stage_half(
    const __hip_bfloat16* g, int ld, __hip_bfloat16* lds, int tid)
{
#pragma unroll
    for (int s = 0; s < 2; ++s) {
        int ci = s * 512 + tid;            // 16B chunk 0..1023
        int r  = ci >> 3;                  // row 0..127
        int c  = (ci & 7) ^ (r & 7);       // logical chunk
        __builtin_amdgcn_global_load_lds(
            (const __attribute__((address_space(1))) void*)(g + (long)r * ld + c * 8),
            (__attribute__((address_space(3))) void*)(lds + ci * 8),
            16, 0, 0);
    }
}
// swizzled LDS read offset (row within 128-row half, kb = col, multiple of 8)
static __device__ __forceinline__ int sw_off(int row, int kb) {
    return row * 64 + ((((kb >> 3) ^ (row & 7))) << 3);
}

// ---- W f32 reg-staging: one 128x64 tile -> 8 f32x4 regs (4 dwordx4) ----
// Same chunk mapping as stage_half so the ds_write lands the identical
// swizzled layout (K fixed = 4096 for gate/up weights).
#define LOADW32(w0, w1, src)                                                   \
    _Pragma("unroll")                                                          \
    for (int s = 0; s < 2; ++s) {                                              \
        int ci = s * 512 + tid;                                                \
        int rr = ci >> 3, cc = (ci & 7) ^ (rr & 7);                            \
        const f32x4* gp = reinterpret_cast<const f32x4*>(                      \
            (src) + (long)rr * 4096 + cc * 8);                                 \
        w0[s] = gp[0]; w1[s] = gp[1];                                          \
    }

#define WRITEW32(w0, w1, ldsbase)                                              \
    _Pragma("unroll")                                                          \
    for (int s = 0; s < 2; ++s) {                                              \
        int ci = s * 512 + tid;                                                \
        short8 pk;                                                             \
        _Pragma("unroll")                                                      \
        for (int e = 0; e < 4; ++e) {                                          \
            __hip_bfloat16 b0 = __float2bfloat16(w0[s][e]);                    \
            __hip_bfloat16 b1 = __float2bfloat16(w1[s][e]);                    \
            pk[e]     = *reinterpret_cast<short*>(&b0);                        \
            pk[4 + e] = *reinterpret_cast<short*>(&b1);                        \
        }                                                                      \
        *reinterpret_cast<short8*>((ldsbase) + ci * 8) = pk;                   \
    }

#define MFMA16(a, b, c) __builtin_amdgcn_mfma_f32_16x16x32_bf16(a, b, c, 0, 0, 0)
#define VM8 asm volatile("s_waitcnt vmcnt(8)" ::: "memory")
#define VM0 asm volatile("s_waitcnt vmcnt(0)" ::: "memory")
#define VM4D do { if (pf) asm volatile("s_waitcnt vmcnt(4)" ::: "memory");     \
                  else    asm volatile("s_waitcnt vmcnt(0)" ::: "memory"); } while (0)

// ============ fused gate+up: H = silu(X Wg^T) * (X Wu^T) ================
// 4-phase / K-tile schedule; A = X bf16 gload_lds (ph1); B = [G|U] bf16 in
// LDS, produced in-kernel from f32 W: issue dwordx4 @ph2, vmcnt(8)@ph3
// (drains A only), vmcnt(0)+cvt+ds_write @ph4 (W loads 2 phases old).
#define FPHASE(cA, cB, IQ, LOADB, STAGE, VMC)                                  \
    {                                                                          \
        short8 af[2][2];                                                       \
        _Pragma("unroll")                                                      \
        for (int ii = 0; ii < 2; ++ii)                                         \
            _Pragma("unroll")                                                  \
            for (int kk = 0; kk < 2; ++kk)                                     \
                af[ii][kk] = *reinterpret_cast<const short8*>(                 \
                    &(cA)[sw_off(wm * 128 + ((IQ) * 2 + ii) * 16 + r16,        \
                                 kk * 32 + g4 * 8)]);                          \
        if (LOADB) {                                                           \
            _Pragma("unroll")                                                  \
            for (int kk = 0; kk < 2; ++kk)                                     \
                _Pragma("unroll")                                              \
                for (int j = 0; j < 2; ++j) {                                  \
                    bg[kk][j] = *reinterpret_cast<const short8*>(              \
                        &(cB)[sw_off(wn * 32 + j * 16 + r16,                   \
                                     kk * 32 + g4 * 8)]);                      \
                    bu[kk][j] = *reinterpret_cast<const short8*>(              \
                        &(cB)[8192 + sw_off(wn * 32 + j * 16 + r16,            \
                                            kk * 32 + g4 * 8)]);               \
                }                                                              \
        }                                                                      \
        STAGE;                                                                 \
        VMC;                                                                   \
        if (LOADB) asm volatile("s_waitcnt lgkmcnt(8)" ::: "memory");          \
        __builtin_amdgcn_s_barrier();                                          \
        asm volatile("s_waitcnt lgkmcnt(0)" ::: "memory");                     \
        __builtin_amdgcn_sched_barrier(0);                                     \
        __builtin_amdgcn_s_setprio(1);                                         \
        _Pragma("unroll")                                                      \
        for (int ii = 0; ii < 2; ++ii)                                         \
            _Pragma("unroll")                                                  \
            for (int j = 0; j < 2; ++j) {                                      \
                accg[(IQ) * 2 + ii][j] = MFMA16(af[ii][0], bg[0][j],           \
                                                accg[(IQ) * 2 + ii][j]);       \
                accg[(IQ) * 2 + ii][j] = MFMA16(af[ii][1], bg[1][j],           \
                                                accg[(IQ) * 2 + ii][j]);       \
                accu[(IQ) * 2 + ii][j] = MFMA16(af[ii][0], bu[0][j],           \
                                                accu[(IQ) * 2 + ii][j]);       \
                accu[(IQ) * 2 + ii][j] = MFMA16(af[ii][1], bu[1][j],           \
                                                accu[(IQ) * 2 + ii][j]);       \
            }                                                                  \
        __builtin_amdgcn_s_setprio(0);                                         \
        __builtin_amdgcn_sched_barrier(0);                                     \
        __builtin_amdgcn_s_barrier();                                          \
    }

// one K-tile t consuming buf XB; pf1: stage A(t+1); pf2: produce B(t+2)
#define GUTILE(XB, PF1, PF2, kA, kW)                                           \
    {                                                                          \
        const __hip_bfloat16* cA = sA + (XB) * 16384;                          \
        const __hip_bfloat16* cB = sB + (XB) * 16384;                          \
        __hip_bfloat16* nA = sA + ((XB) ^ 1) * 16384;                          \
        __hip_bfloat16* wB = sB + (XB) * 16384;                                \
        FPHASE(cA, cB, 0, 1,                                                   \
            if (PF1) { stage_half(Ab + (kA),      4096, nA,        tid);       \
                       stage_half(Ab + h1 + (kA), 4096, nA + 8192, tid); }, ); \
        FPHASE(cA, cB, 1, 0,                                                   \
            if (PF2) { LOADW32(wg0, wg1, G32 + (kW))                           \
                       LOADW32(wu0, wu1, U32 + (kW)) }, );                     \
        FPHASE(cA, cB, 2, 0, , VM8);                                           \
        FPHASE(cA, cB, 3, 0,                                                   \
            { VM0;                                                             \
              if (PF2) { WRITEW32(wg0, wg1, wB)                                \
                         WRITEW32(wu0, wu1, wB + 8192) } }, );                 \
    }

// grid = 1376 GEMM blocks + 160 tail blocks converting Wd f32->bf16.
__global__ __launch_bounds__(512, 2)
void k_gateup(const __hip_bfloat16* __restrict__ X,
              const float* __restrict__ Wg,
              const float* __restrict__ Wu,
              __hip_bfloat16* __restrict__ H,
              const float* __restrict__ Wd32,
              __hip_bfloat16* __restrict__ Wdb)
{
    extern __shared__ __hip_bfloat16 smem[];
    __hip_bfloat16* sA = smem;           // [2 buf][256 rows][64] = 64 KB
    __hip_bfloat16* sB = smem + 32768;   // [2 buf][G 128x64|U 128x64] = 64 KB

    const int tid = threadIdx.x;
    const int bid = blockIdx.x;

    if (bid >= 1376) {                   // ---- fused Wd cvt tail ----
        const long total8 = (long)D_MODEL * D_FF / 8;
        const long stride = 160L * 512;
        for (long i = (long)(bid - 1376) * 512 + tid; i < total8; i += stride) {
            const float4* p = (const float4*)(Wd32 + i * 8);
            float4 v0 = p[0], v1 = p[1];
            float vals[8] = {v0.x, v0.y, v0.z, v0.w, v1.x, v1.y, v1.z, v1.w};
            short8 oo;
#pragma unroll
            for (int j = 0; j < 8; ++j) {
                __hip_bfloat16 b = __float2bfloat16(vals[j]);
                oo[j] = *reinterpret_cast<short*>(&b);
            }
            *reinterpret_cast<short8*>(Wdb + i * 8) = oo;
        }
        return;
    }

    const int lane = tid & 63;
    const int wid  = tid >> 6;
    const int wm = wid >> 2, wn = wid & 3;   // 2M x 4N waves
    const int r16 = lane & 15, g4 = lane >> 4;

    // T1: bijective XCD chunks (1376 = 8*172), m-fastest inside chunk
    const int o = (bid & 7) * 172 + (bid >> 3);
    const int n0 = (o >> 4) * 128;
    const int m0 = (o & 15) * 256;

    const __hip_bfloat16* Ab = X + (long)m0 * 4096;
    const float* G32 = Wg + (long)n0 * 4096;
    const float* U32 = Wu + (long)n0 * 4096;
    const long h1 = (long)128 * 4096;

    f32x4 wg0[2], wg1[2], wu0[2], wu1[2];

    // prologue: A(0) via gload_lds; B(0), B(1) via f32 regs -> LDS
    stage_half(Ab,      4096, sA + 0,    tid);
    stage_half(Ab + h1, 4096, sA + 8192, tid);
    LOADW32(wg0, wg1, G32)
    LOADW32(wu0, wu1, U32)
    VM0;
    WRITEW32(wg0, wg1, sB)
    WRITEW32(wu0, wu1, sB + 8192)
    LOADW32(wg0, wg1, G32 + 64)
    LOADW32(wu0, wu1, U32 + 64)
    VM0;
    WRITEW32(wg0, wg1, sB + 16384)
    WRITEW32(wu0, wu1, sB + 16384 + 8192)
    asm volatile("s_waitcnt lgkmcnt(0)" ::: "memory");
    __builtin_amdgcn_s_barrier();

    f32x4 accg[8][2], accu[8][2];
#pragma unroll
    for (int i = 0; i < 8; ++i)
#pragma unroll
        for (int j = 0; j < 2; ++j) {
            accg[i][j] = (f32x4){0.f, 0.f, 0.f, 0.f};
            accu[i][j] = (f32x4){0.f, 0.f, 0.f, 0.f};
        }

    const int nk = D_MODEL >> 6;  // 64 K-tiles
    short8 bg[2][2], bu[2][2];

    for (int it = 0; it < (nk >> 1); ++it) {
        const int t0 = 2 * it, t1 = 2 * it + 1;
        const bool p1a = (t0 + 1 < nk), p2a = (t0 + 2 < nk);
        const bool p1b = (t1 + 1 < nk), p2b = (t1 + 2 < nk);
        const long kA0 = (long)(t0 + 1) * 64, kW0 = (long)(t0 + 2) * 64;
        const long kA1 = (long)(t1 + 1) * 64, kW1 = (long)(t1 + 2) * 64;
        GUTILE(0, p1a, p2a, kA0, kW0)
        GUTILE(1, p1b, p2b, kA1, kW1)
    }

    // epilogue: h = silu(g) * u
#pragma unroll
    for (int i = 0; i < 8; ++i)
#pragma unroll
        for (int j = 0; j < 2; ++j)
#pragma unroll
            for (int r = 0; r < 4; ++r) {
                long row = m0 + wm * 128 + i * 16 + g4 * 4 + r;
                long col = n0 + wn * 32 + j * 16 + r16;
                float g = accg[i][j][r];
                float u = accu[i][j][r];
                float s = g / (1.f + __expf(-g));
                H[row * D_FF + col] = __float2bfloat16(s * u);
            }
}

// ================= down proj: Y = H Wd^T (f32 out), 8-phase 2-tile ========
#define DPHASE(cA, cB, IQ, LOADB, STAGE, VMC)                                  \
    {                                                                          \
        short8 af[2][2];                                                       \
        _Pragma("unroll")                                                      \
        for (int ii = 0; ii < 2; ++ii)                                         \
            _Pragma("unroll")                                                  \
            for (int kk = 0; kk < 2; ++kk)                                     \
                af[ii][kk] = *reinterpret_cast<const short8*>(                 \
                    &(cA)[sw_off(wm * 128 + ((IQ) * 2 + ii) * 16 + r16,        \
                                 kk * 32 + g4 * 8)]);                          \
        if (LOADB) {                                                           \
            _Pragma("unroll")                                                  \
            for (int kk = 0; kk < 2; ++kk)                                     \
                _Pragma("unroll")                                              \
                for (int j = 0; j < 4; ++j)                                    \
                    bfr[kk][j] = *reinterpret_cast<const short8*>(             \
                        &(cB)[sw_off(wn * 64 + j * 16 + r16,                   \
                                     kk * 32 + g4 * 8)]);                      \
        }                                                                      \
        STAGE;                                                                 \
        VMC;                                                                   \
        if (LOADB) asm volatile("s_waitcnt lgkmcnt(8)" ::: "memory");          \
        __builtin_amdgcn_s_barrier();                                          \
        asm volatile("s_waitcnt lgkmcnt(0)" ::: "memory");                     \
        __builtin_amdgcn_sched_barrier(0);                                     \
        __builtin_amdgcn_s_setprio(1);                                         \
        _Pragma("unroll")                                                      \
        for (int ii = 0; ii < 2; ++ii)                                         \
            _Pragma("unroll")                                                  \
            for (int j = 0; j < 4; ++j) {                                      \
                acc[(IQ) * 2 + ii][j] = MFMA16(af[ii][0], bfr[0][j],           \
                                               acc[(IQ) * 2 + ii][j]);         \
                acc[(IQ) * 2 + ii][j] = MFMA16(af[ii][1], bfr[1][j],           \
                                               acc[(IQ) * 2 + ii][j]);         \
            }                                                                  \
        __builtin_amdgcn_s_setprio(0);                                         \
        __builtin_amdgcn_sched_barrier(0);                                     \
        __builtin_amdgcn_s_barrier();                                          \
    }

__global__ __launch_bounds__(512, 2)
void k_down(const __hip_bfloat16* __restrict__ A,
            const __hip_bfloat16* __restrict__ B,
            float* __restrict__ Y)
{
    extern __shared__ __hip_bfloat16 smem[];
    __hip_bfloat16* sA = smem;           // [2 buf][256][64]
    __hip_bfloat16* sB = smem + 32768;

    const int tid  = threadIdx.x;
    const int lane = tid & 63;
    const int wid  = tid >> 6;
    const int wm = wid >> 2, wn = wid & 3;
    const int r16 = lane & 15, g4 = lane >> 4;

    const int bid = blockIdx.x;          // 256 = 8*32
    const int o = (bid & 7) * 32 + (bid >> 3);
    const int n0 = (o >> 4) << 8;
    const int m0 = (o & 15) << 8;

    const int K = D_FF;
    const int N = D_MODEL;
    const __hip_bfloat16* Ab = A + (long)m0 * K;
    const __hip_bfloat16* Bb = B + (long)n0 * K;
    const long h1 = (long)128 * K;

    stage_half(Ab,            K, sA + 0,             tid);
    stage_half(Ab + h1,       K, sA + 8192,          tid);
    stage_half(Bb,            K, sB + 0,             tid);
    stage_half(Bb + h1,       K, sB + 8192,          tid);
    stage_half(Bb + 64,       K, sB + 16384,         tid);
    stage_half(Bb + h1 + 64,  K, sB + 16384 + 8192,  tid);
    asm volatile("s_waitcnt vmcnt(4)" ::: "memory");
    __builtin_amdgcn_s_barrier();

    f32x4 acc[8][4];
#pragma unroll
    for (int i = 0; i < 8; ++i)
#pragma unroll
        for (int j = 0; j < 4; ++j)
            acc[i][j] = (f32x4){0.f, 0.f, 0.f, 0.f};

    const int nk = K >> 6;        // 172
    const int niter = nk >> 1;    // 86

    for (int it = 0; it < niter; ++it) {
        const bool pf = (it + 1 < niter);
        const long ko  = (long)(2 * it + 1) * 64;
        const long kn2 = (long)(2 * it + 2) * 64;
        const long kn3 = (long)(2 * it + 3) * 64;
        {
            const __hip_bfloat16* cA = sA;
            const __hip_bfloat16* cB = sB;
            short8 bfr[2][4];
            DPHASE(cA, cB, 0, 1,
                stage_half(Ab + ko,      K, sA + 16384,        tid), );
            DPHASE(cA, cB, 1, 0,
                stage_half(Ab + h1 + ko, K, sA + 16384 + 8192, tid), );
            DPHASE(cA, cB, 2, 0,
                if (pf) stage_half(Bb + kn2,      K, sB + 0,    tid), );
            DPHASE(cA, cB, 3, 0,
                if (pf) stage_half(Bb + h1 + kn2, K, sB + 8192, tid), VM4D);
        }
        {
            const __hip_bfloat16* cA = sA + 16384;
            const __hip_bfloat16* cB = sB + 16384;
            short8 bfr[2][4];
            DPHASE(cA, cB, 0, 1,
                if (pf) stage_half(Ab + kn2,      K, sA + 0,    tid), );
            DPHASE(cA, cB, 1, 0,
                if (pf) stage_half(Ab + h1 + kn2, K, sA + 8192, tid), );
            DPHASE(cA, cB, 2, 0,
                if (pf) stage_half(Bb + kn3,      K, sB + 16384, tid), );
            DPHASE(cA, cB, 3, 0,
                if (pf) stage_half(Bb + h1 + kn3, K, sB + 16384 + 8192, tid), VM4D);
        }
    }

#pragma unroll
    for (int i = 0; i < 8; ++i)
#pragma unroll
        for (int j = 0; j < 4; ++j)
#pragma unroll
            for (int r = 0; r < 4; ++r) {
                long row = m0 + wm * 128 + i * 16 + g4 * 4 + r;
                long col = n0 + wn * 64 + j * 16 + r16;
                Y[row * N + col] = acc[i][j][r];
            }
}

extern "C" void kernel_launch(void* const* d_in, const int* in_sizes, int n_in,
                              void* d_out, int out_size, void* d_ws, size_t ws_size,
                              hipStream_t stream) {
    const float* x  = (const float*)d_in[0];
    const float* wg = (const float*)d_in[1];
    const float* wu = (const float*)d_in[2];
    const float* wd = (const float*)d_in[3];
    float* y = (float*)d_out;

    char* ws = (char*)d_ws;
    const size_t szX  = (size_t)NTOK * D_MODEL * 2;
    const size_t szWd = (size_t)D_MODEL * D_FF * 2;
    __hip_bfloat16* Xb  = (__hip_bfloat16*)(ws);
    __hip_bfloat16* Wdb = (__hip_bfloat16*)(ws + szX);
    __hip_bfloat16* Hb  = (__hip_bfloat16*)(ws + szX + szWd);
    (void)ws_size; (void)out_size; (void)n_in; (void)in_sizes;

    const int SMEM = 131072;  // 128 KiB for both GEMMs
    hipFuncSetAttribute((const void*)k_gateup, hipFuncAttributeMaxDynamicSharedMemorySize, SMEM);
    hipFuncSetAttribute((const void*)k_down,   hipFuncAttributeMaxDynamicSharedMemorySize, SMEM);

    const int nX = NTOK * D_MODEL / 8;
    k_cvt<<<(nX + 255) / 256, 256, 0, stream>>>(x, Xb, nX);

    // fused: Hb = silu(X Wg^T) * (X Wu^T); W read f32, cvt in staging;
    // tail blocks (1376..1535) convert Wd f32->bf16 for k_down.
    k_gateup<<<1536, 512, SMEM, stream>>>(Xb, wg, wu, Hb, wd, Wdb);
    // down:  Y = Hb Wd^T (f32 out)
    k_down<<<256, 512, SMEM, stream>>>(Hb, Wdb, y);
}

// Round 14
// 1018.959 us; speedup vs baseline: 1.1831x; 1.1831x over previous
//
#include <hip/hip_runtime.h>
#include <hip/hip_bf16.h>

#define D_MODEL 4096
#define D_FF    11008
#define NTOK    4096   // 2*2048 tokens

typedef __attribute__((ext_vector_type(8))) short short8;
typedef __attribute__((ext_vector_type(4))) float f32x4;

// ---------------- fp32 -> bf16 convert (8 elems/thread) ----------------
__global__ void k_cvt(const float* __restrict__ in, __hip_bfloat16* __restrict__ out, int n8) {
    int i = blockIdx.x * blockDim.x + threadIdx.x;
    if (i >= n8) return;
    const float4* p = (const float4*)in;
    float4 v0 = p[(size_t)i * 2];
    float4 v1 = p[(size_t)i * 2 + 1];
    float vals[8] = {v0.x, v0.y, v0.z, v0.w, v1.x, v1.y, v1.z, v1.w};
    short8 o;
#pragma unroll
    for (int j = 0; j < 8; ++j) {
        __hip_bfloat16 b = __float2bfloat16(vals[j]);
        o[j] = *reinterpret_cast<short*>(&b);
    }
    *reinterpret_cast<short8*>(out + (size_t)i * 8) = o;
}

// ---- stage one 128x64 bf16 half-tile via global_load_lds ----
// LDS dest linear; swizzle via permuted GLOBAL source chunk (rule #21):
// physical chunk p of row r holds logical chunk p ^ (r&7).
static __device__ __forceinline__ void stage_half(
    const __hip_bfloat16* g, int ld, __hip_bfloat16* lds, int tid)
{
#pragma unroll
    for (int s = 0; s < 2; ++s) {
        int ci = s * 512 + tid;            // 16B chunk 0..1023
        int r  = ci >> 3;                  // row 0..127
        int c  = (ci & 7) ^ (r & 7);       // logical chunk
        __builtin_amdgcn_global_load_lds(
            (const __attribute__((address_space(1))) void*)(g + (long)r * ld + c * 8),
            (__attribute__((address_space(3))) void*)(lds + ci * 8),
            16, 0, 0);
    }
}
// swizzled LDS read offset (row within 256-row tile, kb = col, multiple of 8)
static __device__ __forceinline__ int sw_off(int row, int kb) {
    return row * 64 + ((((kb >> 3) ^ (row & 7))) << 3);
}

#define MFMA16(a, b, c) __builtin_amdgcn_mfma_f32_16x16x32_bf16(a, b, c, 0, 0, 0)
#define VM4  asm volatile("s_waitcnt vmcnt(4)" ::: "memory")
#define VM0A asm volatile("s_waitcnt vmcnt(0)" ::: "memory")
#define VM4D do { if (pf) asm volatile("s_waitcnt vmcnt(4)" ::: "memory");     \
                  else    asm volatile("s_waitcnt vmcnt(0)" ::: "memory"); } while (0)

// ============ fused gate+up: H = silu(X Wg^T) * (X Wu^T) ================
// 8-phase / 2 K-tile schedule with A-RING-3 (A staged 2 K-tiles ahead,
// consumed 6-8 phases after issue; B dbuf as before, 5-6 phase window).
// Per-phase issue counts and vmcnt placement identical to the proven R10
// schedule — only the A slot indices (compile-time, period-3) change.
#define FPHASE(cA, cB, IQ, LOADB, STAGE, VMC)                                  \
    {                                                                          \
        short8 af[2][2];                                                       \
        _Pragma("unroll")                                                      \
        for (int ii = 0; ii < 2; ++ii)                                         \
            _Pragma("unroll")                                                  \
            for (int kk = 0; kk < 2; ++kk)                                     \
                af[ii][kk] = *reinterpret_cast<const short8*>(                 \
                    &(cA)[sw_off(wm * 128 + ((IQ) * 2 + ii) * 16 + r16,        \
                                 kk * 32 + g4 * 8)]);                          \
        if (LOADB) {                                                           \
            _Pragma("unroll")                                                  \
            for (int kk = 0; kk < 2; ++kk)                                     \
                _Pragma("unroll")                                              \
                for (int j = 0; j < 2; ++j) {                                  \
                    bg[kk][j] = *reinterpret_cast<const short8*>(              \
                        &(cB)[sw_off(wn * 32 + j * 16 + r16,                   \
                                     kk * 32 + g4 * 8)]);                      \
                    bu[kk][j] = *reinterpret_cast<const short8*>(              \
                        &(cB)[8192 + sw_off(wn * 32 + j * 16 + r16,            \
                                            kk * 32 + g4 * 8)]);               \
                }                                                              \
        }                                                                      \
        STAGE;                                                                 \
        VMC;                                                                   \
        if (LOADB) asm volatile("s_waitcnt lgkmcnt(8)" ::: "memory");          \
        __builtin_amdgcn_s_barrier();                                          \
        asm volatile("s_waitcnt lgkmcnt(0)" ::: "memory");                     \
        __builtin_amdgcn_sched_barrier(0);                                     \
        __builtin_amdgcn_s_setprio(1);                                         \
        _Pragma("unroll")                                                      \
        for (int ii = 0; ii < 2; ++ii)                                         \
            _Pragma("unroll")                                                  \
            for (int j = 0; j < 2; ++j) {                                      \
                accg[(IQ) * 2 + ii][j] = MFMA16(af[ii][0], bg[0][j],           \
                                                accg[(IQ) * 2 + ii][j]);       \
                accg[(IQ) * 2 + ii][j] = MFMA16(af[ii][1], bg[1][j],           \
                                                accg[(IQ) * 2 + ii][j]);       \
                accu[(IQ) * 2 + ii][j] = MFMA16(af[ii][0], bu[0][j],           \
                                                accu[(IQ) * 2 + ii][j]);       \
                accu[(IQ) * 2 + ii][j] = MFMA16(af[ii][1], bu[1][j],           \
                                                accu[(IQ) * 2 + ii][j]);       \
            }                                                                  \
        __builtin_amdgcn_s_setprio(0);                                         \
        __builtin_amdgcn_sched_barrier(0);                                     \
        __builtin_amdgcn_s_barrier();                                          \
    }

// One group = K-tiles (2*IT, 2*IT+1). Consume A slots CS0/CS1; stage
// A(2IT+2)->WS0 (ph1-2), A(2IT+3)->WS1 (ph5-6); B(2IT+2)->buf0 (ph3-4),
// B(2IT+3)->buf1 (ph7-8). WS0 distinct from CS0/CS1; WS1==CS0 written
// only after its last read (ph4 barrier). B-frags are reg-captured at ph1,
// so overwriting the B buf at ph3-4 is race-free (two barriers after ph1).
#define GUGROUP(IT, CS0, CS1, WS0, WS1, PF, VML)                               \
    {                                                                          \
        const long kA2 = (long)(2 * (IT) + 2) * 64;                            \
        const long kA3 = kA2 + 64;                                             \
        const __hip_bfloat16* cA0 = sA + (CS0) * 16384;                        \
        const __hip_bfloat16* cA1 = sA + (CS1) * 16384;                        \
        __hip_bfloat16* w0 = sA + (WS0) * 16384;                               \
        __hip_bfloat16* w1 = sA + (WS1) * 16384;                               \
        short8 bg[2][2], bu[2][2];                                             \
        FPHASE(cA0, sB, 0, 1,                                                  \
            if (PF) stage_half(Ab + kA2,      4096, w0,        tid), );        \
        FPHASE(cA0, sB, 1, 0,                                                  \
            if (PF) stage_half(Ab + h1 + kA2, 4096, w0 + 8192, tid), );        \
        FPHASE(cA0, sB, 2, 0,                                                  \
            if (PF) stage_half(Gb + kA2, 4096, sB,        tid), );             \
        FPHASE(cA0, sB, 3, 0,                                                  \
            if (PF) stage_half(Ub + kA2, 4096, sB + 8192, tid), VML);          \
        FPHASE(cA1, sB + 16384, 0, 1,                                          \
            if (PF) stage_half(Ab + kA3,      4096, w1,        tid), );        \
        FPHASE(cA1, sB + 16384, 1, 0,                                          \
            if (PF) stage_half(Ab + h1 + kA3, 4096, w1 + 8192, tid), );        \
        FPHASE(cA1, sB + 16384, 2, 0,                                          \
            if (PF) stage_half(Gb + kA3, 4096, sB + 16384,        tid), );     \
        FPHASE(cA1, sB + 16384, 3, 0,                                          \
            if (PF) stage_half(Ub + kA3, 4096, sB + 16384 + 8192, tid), VML);  \
    }

// grid = 1376 GEMM blocks + 160 tail blocks converting Wd f32->bf16.
__global__ __launch_bounds__(512, 2)
void k_gateup(const __hip_bfloat16* __restrict__ X,
              const __hip_bfloat16* __restrict__ Wg,
              const __hip_bfloat16* __restrict__ Wu,
              __hip_bfloat16* __restrict__ H,
              const float* __restrict__ Wd32,
              __hip_bfloat16* __restrict__ Wdb)
{
    extern __shared__ __hip_bfloat16 smem[];
    __hip_bfloat16* sA = smem;            // 3 ring slots x 32 KB (256x64 each)
    __hip_bfloat16* sB = smem + 49152;    // 2 bufs x 32 KB ([G 128x64|U 128x64])

    const int tid = threadIdx.x;
    const int bid = blockIdx.x;

    if (bid >= 1376) {                    // ---- fused Wd cvt tail ----
        const long total8 = (long)D_MODEL * D_FF / 8;
        const long stride = 160L * 512;
        for (long i = (long)(bid - 1376) * 512 + tid; i < total8; i += stride) {
            const float4* p = (const float4*)(Wd32 + i * 8);
            float4 v0 = p[0], v1 = p[1];
            float vals[8] = {v0.x, v0.y, v0.z, v0.w, v1.x, v1.y, v1.z, v1.w};
            short8 oo;
#pragma unroll
            for (int j = 0; j < 8; ++j) {
                __hip_bfloat16 b = __float2bfloat16(vals[j]);
                oo[j] = *reinterpret_cast<short*>(&b);
            }
            *reinterpret_cast<short8*>(Wdb + i * 8) = oo;
        }
        return;
    }

    const int lane = tid & 63;
    const int wid  = tid >> 6;
    const int wm = wid >> 2, wn = wid & 3;   // 2M x 4N waves
    const int r16 = lane & 15, g4 = lane >> 4;

    // T1: bijective XCD chunks (1376 = 8*172), m-fastest inside chunk
    const int o = (bid & 7) * 172 + (bid >> 3);
    const int n0 = (o >> 4) * 128;
    const int m0 = (o & 15) * 256;

    const __hip_bfloat16* Ab = X  + (long)m0 * 4096;
    const __hip_bfloat16* Gb = Wg + (long)n0 * 4096;
    const __hip_bfloat16* Ub = Wu + (long)n0 * 4096;
    const long h1 = (long)128 * 4096;

    // prologue: A(0)->slot0, B(0)->buf0, A(1)->slot1, B(1)->buf1 (16 loads);
    // need A0+B0 (oldest 8) -> vmcnt(8).
    stage_half(Ab,           4096, sA + 0,              tid);
    stage_half(Ab + h1,      4096, sA + 8192,           tid);
    stage_half(Gb,           4096, sB + 0,              tid);
    stage_half(Ub,           4096, sB + 8192,           tid);
    stage_half(Ab + 64,      4096, sA + 16384,          tid);
    stage_half(Ab + h1 + 64, 4096, sA + 16384 + 8192,   tid);
    stage_half(Gb + 64,      4096, sB + 16384,          tid);
    stage_half(Ub + 64,      4096, sB + 16384 + 8192,   tid);
    asm volatile("s_waitcnt vmcnt(8)" ::: "memory");
    __builtin_amdgcn_s_barrier();

    f32x4 accg[8][2], accu[8][2];
#pragma unroll
    for (int i = 0; i < 8; ++i)
#pragma unroll
        for (int j = 0; j < 2; ++j) {
            accg[i][j] = (f32x4){0.f, 0.f, 0.f, 0.f};
            accu[i][j] = (f32x4){0.f, 0.f, 0.f, 0.f};
        }

    // 32 groups of 2 K-tiles; slot pattern period 3 -> 10 supergroups + 2 tails
    for (int j = 0; j < 10; ++j) {
        const int it = 3 * j;
        GUGROUP(it,     0, 1, 2, 0, true, VM4)
        GUGROUP(it + 1, 2, 0, 1, 2, true, VM4)
        GUGROUP(it + 2, 1, 2, 0, 1, true, VM4)
    }
    GUGROUP(30, 0, 1, 2, 0, true,  VM4)    // stages tiles 62,63
    GUGROUP(31, 2, 0, 1, 2, false, VM0A)   // drain

    // epilogue: h = silu(g) * u
#pragma unroll
    for (int i = 0; i < 8; ++i)
#pragma unroll
        for (int j = 0; j < 2; ++j)
#pragma unroll
            for (int r = 0; r < 4; ++r) {
                long row = m0 + wm * 128 + i * 16 + g4 * 4 + r;
                long col = n0 + wn * 32 + j * 16 + r16;
                float g = accg[i][j][r];
                float u = accu[i][j][r];
                float s = g / (1.f + __expf(-g));
                H[row * D_FF + col] = __float2bfloat16(s * u);
            }
}

// ================= down proj: Y = H Wd^T (f32 out), 8-phase 2-tile ========
#define DPHASE(cA, cB, IQ, LOADB, STAGE, VMC)                                  \
    {                                                                          \
        short8 af[2][2];                                                       \
        _Pragma("unroll")                                                      \
        for (int ii = 0; ii < 2; ++ii)                                         \
            _Pragma("unroll")                                                  \
            for (int kk = 0; kk < 2; ++kk)                                     \
                af[ii][kk] = *reinterpret_cast<const short8*>(                 \
                    &(cA)[sw_off(wm * 128 + ((IQ) * 2 + ii) * 16 + r16,        \
                                 kk * 32 + g4 * 8)]);                          \
        if (LOADB) {                                                           \
            _Pragma("unroll")                                                  \
            for (int kk = 0; kk < 2; ++kk)                                     \
                _Pragma("unroll")                                              \
                for (int j = 0; j < 4; ++j)                                    \
                    bfr[kk][j] = *reinterpret_cast<const short8*>(             \
                        &(cB)[sw_off(wn * 64 + j * 16 + r16,                   \
                                     kk * 32 + g4 * 8)]);                      \
        }                                                                      \
        STAGE;                                                                 \
        VMC;                                                                   \
        if (LOADB) asm volatile("s_waitcnt lgkmcnt(8)" ::: "memory");          \
        __builtin_amdgcn_s_barrier();                                          \
        asm volatile("s_waitcnt lgkmcnt(0)" ::: "memory");                     \
        __builtin_amdgcn_sched_barrier(0);                                     \
        __builtin_amdgcn_s_setprio(1);                                         \
        _Pragma("unroll")                                                      \
        for (int ii = 0; ii < 2; ++ii)                                         \
            _Pragma("unroll")                                                  \
            for (int j = 0; j < 4; ++j) {                                      \
                acc[(IQ) * 2 + ii][j] = MFMA16(af[ii][0], bfr[0][j],           \
                                               acc[(IQ) * 2 + ii][j]);         \
                acc[(IQ) * 2 + ii][j] = MFMA16(af[ii][1], bfr[1][j],           \
                                               acc[(IQ) * 2 + ii][j]);         \
            }                                                                  \
        __builtin_amdgcn_s_setprio(0);                                         \
        __builtin_amdgcn_sched_barrier(0);                                     \
        __builtin_amdgcn_s_barrier();                                          \
    }

__global__ __launch_bounds__(512, 2)
void k_down(const __hip_bfloat16* __restrict__ A,
            const __hip_bfloat16* __restrict__ B,
            float* __restrict__ Y)
{
    extern __shared__ __hip_bfloat16 smem[];
    __hip_bfloat16* sA = smem;           // [2 buf][256][64]
    __hip_bfloat16* sB = smem + 32768;

    const int tid  = threadIdx.x;
    const int lane = tid & 63;
    const int wid  = tid >> 6;
    const int wm = wid >> 2, wn = wid & 3;
    const int r16 = lane & 15, g4 = lane >> 4;

    const int bid = blockIdx.x;          // 256 = 8*32
    const int o = (bid & 7) * 32 + (bid >> 3);
    const int n0 = (o >> 4) << 8;
    const int m0 = (o & 15) << 8;

    const int K = D_FF;
    const int N = D_MODEL;
    const __hip_bfloat16* Ab = A + (long)m0 * K;
    const __hip_bfloat16* Bb = B + (long)n0 * K;
    const long h1 = (long)128 * K;

    stage_half(Ab,            K, sA + 0,             tid);
    stage_half(Ab + h1,       K, sA + 8192,          tid);
    stage_half(Bb,            K, sB + 0,             tid);
    stage_half(Bb + h1,       K, sB + 8192,          tid);
    stage_half(Bb + 64,       K, sB + 16384,         tid);
    stage_half(Bb + h1 + 64,  K, sB + 16384 + 8192,  tid);
    asm volatile("s_waitcnt vmcnt(4)" ::: "memory");
    __builtin_amdgcn_s_barrier();

    f32x4 acc[8][4];
#pragma unroll
    for (int i = 0; i < 8; ++i)
#pragma unroll
        for (int j = 0; j < 4; ++j)
            acc[i][j] = (f32x4){0.f, 0.f, 0.f, 0.f};

    const int nk = K >> 6;        // 172
    const int niter = nk >> 1;    // 86

    for (int it = 0; it < niter; ++it) {
        const bool pf = (it + 1 < niter);
        const long ko  = (long)(2 * it + 1) * 64;
        const long kn2 = (long)(2 * it + 2) * 64;
        const long kn3 = (long)(2 * it + 3) * 64;
        {
            const __hip_bfloat16* cA = sA;
            const __hip_bfloat16* cB = sB;
            short8 bfr[2][4];
            DPHASE(cA, cB, 0, 1,
                stage_half(Ab + ko,      K, sA + 16384,        tid), );
            DPHASE(cA, cB, 1, 0,
                stage_half(Ab + h1 + ko, K, sA + 16384 + 8192, tid), );
            DPHASE(cA, cB, 2, 0,
                if (pf) stage_half(Bb + kn2,      K, sB + 0,    tid), );
            DPHASE(cA, cB, 3, 0,
                if (pf) stage_half(Bb + h1 + kn2, K, sB + 8192, tid), VM4D);
        }
        {
            const __hip_bfloat16* cA = sA + 16384;
            const __hip_bfloat16* cB = sB + 16384;
            short8 bfr[2][4];
            DPHASE(cA, cB, 0, 1,
                if (pf) stage_half(Ab + kn2,      K, sA + 0,    tid), );
            DPHASE(cA, cB, 1, 0,
                if (pf) stage_half(Ab + h1 + kn2, K, sA + 8192, tid), );
            DPHASE(cA, cB, 2, 0,
                if (pf) stage_half(Bb + kn3,      K, sB + 16384, tid), );
            DPHASE(cA, cB, 3, 0,
                if (pf) stage_half(Bb + h1 + kn3, K, sB + 16384 + 8192, tid), VM4D);
        }
    }

#pragma unroll
    for (int i = 0; i < 8; ++i)
#pragma unroll
        for (int j = 0; j < 4; ++j)
#pragma unroll
            for (int r = 0; r < 4; ++r) {
                long row = m0 + wm * 128 + i * 16 + g4 * 4 + r;
                long col = n0 + wn * 64 + j * 16 + r16;
                Y[row * N + col] = acc[i][j][r];
            }
}

extern "C" void kernel_launch(void* const* d_in, const int* in_sizes, int n_in,
                              void* d_out, int out_size, void* d_ws, size_t ws_size,
                              hipStream_t stream) {
    const float* x  = (const float*)d_in[0];
    const float* wg = (const float*)d_in[1];
    const float* wu = (const float*)d_in[2];
    const float* wd = (const float*)d_in[3];
    float* y = (float*)d_out;

    char* ws = (char*)d_ws;
    const size_t szX = (size_t)NTOK * D_MODEL * 2;
    const size_t szW = (size_t)D_FF * D_MODEL * 2;
    __hip_bfloat16* Xb  = (__hip_bfloat16*)(ws);
    __hip_bfloat16* Wgb = (__hip_bfloat16*)(ws + szX);
    __hip_bfloat16* Wub = (__hip_bfloat16*)(ws + szX + szW);
    __hip_bfloat16* Wdb = (__hip_bfloat16*)(ws + szX + 2 * szW);
    __hip_bfloat16* Hb  = (__hip_bfloat16*)(ws + szX + 3 * szW);
    (void)ws_size; (void)out_size; (void)n_in; (void)in_sizes;

    const int SMEM_GU = 163840;  // 160 KiB: A ring-3 96KB + B dbuf 64KB
    const int SMEM_D  = 131072;  // 128 KiB
    hipFuncSetAttribute((const void*)k_gateup, hipFuncAttributeMaxDynamicSharedMemorySize, SMEM_GU);
    hipFuncSetAttribute((const void*)k_down,   hipFuncAttributeMaxDynamicSharedMemorySize, SMEM_D);

    const int nX = NTOK * D_MODEL / 8;
    const int nW = D_FF * D_MODEL / 8;
    k_cvt<<<(nX + 255) / 256, 256, 0, stream>>>(x, Xb, nX);
    k_cvt<<<(nW + 255) / 256, 256, 0, stream>>>(wg, Wgb, nW);
    k_cvt<<<(nW + 255) / 256, 256, 0, stream>>>(wu, Wub, nW);

    // fused: Hb = silu(X Wg^T) * (X Wu^T); tail blocks (1376..1535) cvt Wd
    k_gateup<<<1536, 512, SMEM_GU, stream>>>(Xb, Wgb, Wub, Hb, wd, Wdb);
    // down:  Y = Hb Wd^T (f32 out)
    k_down<<<256, 512, SMEM_D, stream>>>(Hb, Wdb, y);
}